// Round 7
// baseline (1044.069 us; speedup 1.0000x reference)
//
#include <hip/hip_runtime.h>
#include <hip/hip_cooperative_groups.h>

// GATv2 2-layer encoder. R7: dispatch-count collapse 15 -> 5.
//  - build_kernel (cooperative): zero+weight-cvt -> deg atomics -> device scan
//    -> scatter, edges cached in registers across phases.
//  - mu head fused into layer-1 gat_edge epilogue (no h1 round-trip).
//  - gat_edge main loop / gemm_fused unchanged from R6 (known-good).
// N=50000, E=800000, IN=256, H=4, C=64, LAT=32, ED=3.

#define NN  50000
#define EE  800000
#define HC  256     // H*C
#define NSLOPE 0.2f
#define SCAN_B ((NN + 255) / 256)        // 196 scan segments
#define NB_BUILD ((EE / 4 + 255) / 256)  // 782 blocks (>= SCAN_B)

namespace cg = cooperative_groups;

typedef float f32x4 __attribute__((ext_vector_type(4)));
typedef short bf16x8 __attribute__((ext_vector_type(8)));

__device__ __forceinline__ unsigned short f2b(float f) {   // fp32 -> bf16 RNE
    unsigned u = __float_as_uint(f);
    u += 0x7FFFu + ((u >> 16) & 1u);
    return (unsigned short)(u >> 16);
}
__device__ __forceinline__ float b2f(unsigned short h) {
    return __uint_as_float((unsigned)h << 16);
}

// ---------------- cooperative CSR build + weight cvt ----------------
struct BuildParams {
    const int* ei; const float* ea;
    int* deg; int* rows; int* curs; int* bsum; int* boff;
    float4* csr;
    const float* Wl0; const float* Wr0; const float* Wl1; const float* Wr1;
    unsigned short* WT0h; unsigned short* WT0l;
    unsigned short* WT1h; unsigned short* WT1l;
};

__global__ __launch_bounds__(256) void build_kernel(BuildParams P)
{
    cg::grid_group grid = cg::this_grid();
    const int tid = threadIdx.x;
    const int gid = blockIdx.x * 256 + tid;
    const int gsz = gridDim.x * 256;
    __shared__ int sh[256];

    // ---- phase 0: zero deg + weight transpose/split ----
    for (int i = gid; i < NN; i += gsz) P.deg[i] = 0;
    for (int i = gid; i < 256 * 256; i += gsz) {
        int k = i >> 8, c = i & 255;
        float v = P.Wl0[i];
        unsigned short h = f2b(v);
        P.WT0h[c * 256 + k] = h; P.WT0l[c * 256 + k] = f2b(v - b2f(h));
        v = P.Wr0[i];
        h = f2b(v);
        P.WT0h[(256 + c) * 256 + k] = h; P.WT0l[(256 + c) * 256 + k] = f2b(v - b2f(h));
    }
    for (int i = gid; i < 64 * 256; i += gsz) {
        int k = i >> 8, c = i & 255;
        float v = P.Wl1[i];
        unsigned short h = f2b(v);
        P.WT1h[c * 64 + k] = h; P.WT1l[c * 64 + k] = f2b(v - b2f(h));
        v = P.Wr1[i];
        h = f2b(v);
        P.WT1h[(256 + c) * 64 + k] = h; P.WT1l[(256 + c) * 64 + k] = f2b(v - b2f(h));
    }
    // cache this thread's 4 edges in registers (reused in deg + scatter)
    const int ii = gid;
    const bool ev = ii < EE / 4;
    int4 s4 = {0, 0, 0, 0}, d4 = {0, 0, 0, 0};
    float4 e0 = {0, 0, 0, 0}, e1 = {0, 0, 0, 0}, e2 = {0, 0, 0, 0};
    if (ev) {
        s4 = ((const int4*)P.ei)[ii];
        d4 = ((const int4*)(P.ei + EE))[ii];
        e0 = ((const float4*)P.ea)[ii * 3 + 0];
        e1 = ((const float4*)P.ea)[ii * 3 + 1];
        e2 = ((const float4*)P.ea)[ii * 3 + 2];
    }
    grid.sync();

    // ---- phase 1: degree atomics ----
    if (ev) {
        atomicAdd(&P.deg[d4.x], 1);
        atomicAdd(&P.deg[d4.y], 1);
        atomicAdd(&P.deg[d4.z], 1);
        atomicAdd(&P.deg[d4.w], 1);
    }
    grid.sync();

    // ---- phase 2: per-segment inclusive scan ----
    if (blockIdx.x < SCAN_B) {
        int i = blockIdx.x * 256 + tid;
        int v = (i < NN) ? P.deg[i] : 0;
        sh[tid] = v;
        __syncthreads();
        for (int off = 1; off < 256; off <<= 1) {
            int u = (tid >= off) ? sh[tid - off] : 0;
            __syncthreads();
            sh[tid] += u;
            __syncthreads();
        }
        if (i < NN) P.rows[i] = sh[tid] - v;     // exclusive within segment
        if (tid == 255) P.bsum[blockIdx.x] = sh[255];
    }
    grid.sync();

    // ---- phase 3: scan of segment sums (block 0) ----
    if (blockIdx.x == 0) {
        int v = (tid < SCAN_B) ? P.bsum[tid] : 0;
        sh[tid] = v;
        __syncthreads();
        for (int off = 1; off < 256; off <<= 1) {
            int u = (tid >= off) ? sh[tid - off] : 0;
            __syncthreads();
            sh[tid] += u;
            __syncthreads();
        }
        if (tid < SCAN_B) P.boff[tid] = sh[tid] - v;
    }
    grid.sync();

    // ---- phase 4: apply segment offsets ----
    if (blockIdx.x < SCAN_B) {
        int i = blockIdx.x * 256 + tid;
        if (i < NN) {
            int v = P.rows[i] + P.boff[blockIdx.x];
            P.rows[i] = v;
            P.curs[i] = v;
        }
    }
    if (gid == 0) P.rows[NN] = EE;
    grid.sync();

    // ---- phase 5: scatter (registers still hold the edge data) ----
    if (ev) {
        int p0 = atomicAdd(&P.curs[d4.x], 1);
        int p1 = atomicAdd(&P.curs[d4.y], 1);
        int p2 = atomicAdd(&P.curs[d4.z], 1);
        int p3 = atomicAdd(&P.curs[d4.w], 1);
        P.csr[p0] = make_float4(__int_as_float(s4.x), e0.x, e0.y, e0.z);
        P.csr[p1] = make_float4(__int_as_float(s4.y), e0.w, e1.x, e1.y);
        P.csr[p2] = make_float4(__int_as_float(s4.z), e1.z, e1.w, e2.x);
        P.csr[p3] = make_float4(__int_as_float(s4.w), e2.y, e2.z, e2.w);
    }
}

// ---------------- fused split-bf16 MFMA GEMM: [xl|xr] = A @ [Wl|Wr] + bias ----------
__global__ __launch_bounds__(256) void gemm_fused(
    const float* __restrict__ A,
    const unsigned short* __restrict__ BTh, const unsigned short* __restrict__ BTl,
    const float* __restrict__ bias0, const float* __restrict__ bias1,
    float* __restrict__ C0, float* __restrict__ C1,
    int M, int K)
{
    __shared__ unsigned short Ah[64][36], Al[64][36];    // 72B row stride: conflict-free
    __shared__ unsigned short Bh[256][36], Bl[256][36];  // total LDS 46080 B
    const int tid = threadIdx.x;
    const int bm = blockIdx.y << 6;
    const int bn = blockIdx.x << 8;        // 0 or 256
    const int w  = tid >> 6, l = tid & 63;
    const int wr = w >> 1, wc = w & 1;
    const int lr = l & 15, lk = l >> 4;

    f32x4 acc[2][8];
#pragma unroll
    for (int a = 0; a < 2; a++)
#pragma unroll
        for (int b = 0; b < 8; b++) acc[a][b] = (f32x4){0.f, 0.f, 0.f, 0.f};

    const int ar = tid >> 2, ac = (tid & 3) << 3;   // A stage: row 0..63, k-chunk {0,8,16,24}

    for (int k0 = 0; k0 < K; k0 += 32) {
        // ---- stage A (fp32 -> bf16 hi/lo split in registers) ----
        float av[8];
        if (bm + ar < M) {
            *(float4*)&av[0] = *(const float4*)&A[(size_t)(bm + ar) * K + k0 + ac];
            *(float4*)&av[4] = *(const float4*)&A[(size_t)(bm + ar) * K + k0 + ac + 4];
        } else {
#pragma unroll
            for (int j = 0; j < 8; j++) av[j] = 0.f;
        }
        unsigned hp[4], lp[4];
#pragma unroll
        for (int j = 0; j < 4; j++) {
            unsigned short h0 = f2b(av[2 * j]),     h1 = f2b(av[2 * j + 1]);
            unsigned short l0 = f2b(av[2 * j]     - b2f(h0));
            unsigned short l1 = f2b(av[2 * j + 1] - b2f(h1));
            hp[j] = (unsigned)h0 | ((unsigned)h1 << 16);
            lp[j] = (unsigned)l0 | ((unsigned)l1 << 16);
        }
        *(uint4*)&Ah[ar][ac] = make_uint4(hp[0], hp[1], hp[2], hp[3]);
        *(uint4*)&Al[ar][ac] = make_uint4(lp[0], lp[1], lp[2], lp[3]);
        // ---- stage B (bf16 planes, pure copy): 256 rows x 64B, 4 reps ----
#pragma unroll
        for (int rep = 0; rep < 4; rep++) {
            int i  = (rep << 8) + tid;
            int rb = i >> 2, cb = (i & 3) << 3;
            *(uint4*)&Bh[rb][cb] = *(const uint4*)&BTh[(size_t)(bn + rb) * K + k0 + cb];
            *(uint4*)&Bl[rb][cb] = *(const uint4*)&BTl[(size_t)(bn + rb) * K + k0 + cb];
        }
        __syncthreads();

        bf16x8 afh[2], afl[2];
#pragma unroll
        for (int a = 0; a < 2; a++) {
            afh[a] = *(const bf16x8*)&Ah[wr * 32 + a * 16 + lr][lk << 3];
            afl[a] = *(const bf16x8*)&Al[wr * 32 + a * 16 + lr][lk << 3];
        }
#pragma unroll
        for (int b = 0; b < 8; b++) {
            bf16x8 bh  = *(const bf16x8*)&Bh[wc * 128 + b * 16 + lr][lk << 3];
            bf16x8 bl_ = *(const bf16x8*)&Bl[wc * 128 + b * 16 + lr][lk << 3];
#pragma unroll
            for (int a = 0; a < 2; a++) {
                acc[a][b] = __builtin_amdgcn_mfma_f32_16x16x32_bf16(afh[a], bh,  acc[a][b], 0, 0, 0);
                acc[a][b] = __builtin_amdgcn_mfma_f32_16x16x32_bf16(afh[a], bl_, acc[a][b], 0, 0, 0);
                acc[a][b] = __builtin_amdgcn_mfma_f32_16x16x32_bf16(afl[a], bh,  acc[a][b], 0, 0, 0);
            }
        }
        __syncthreads();
    }

    const float* bias = (bn == 0) ? bias0 : bias1;
    float* C = (bn == 0) ? C0 : C1;
#pragma unroll
    for (int a = 0; a < 2; a++) {
        int rbase = bm + wr * 32 + a * 16 + (lk << 2);
#pragma unroll
        for (int b = 0; b < 8; b++) {
            int c = wc * 128 + b * 16 + lr;        // 0..255 within half
            float bs = bias[c];
#pragma unroll
            for (int i = 0; i < 4; i++) {
                int rg = rbase + i;
                if (rg < M) C[(size_t)rg * HC + c] = acc[a][b][i] + bs;
            }
        }
    }
}

// ---------------- Fused per-node edge attention + aggregation (R3 structure) --------
// One wave per node. lane = h*16 + q; lane owns channels [4q..4q+3] of head h.
// FUSE=1: mu head (h @ Wmu + bmu) fused into the epilogue, writes final out.
template<int FUSE>
__global__ __launch_bounds__(256) void gat_edge(
    const float* __restrict__ xl, const float* __restrict__ xr,
    const float4* __restrict__ csr, const int* __restrict__ row_start,
    const float* __restrict__ att, const float* __restrict__ We,
    const float* __restrict__ bias, float* __restrict__ out,
    const float* __restrict__ Wmu, const float* __restrict__ bmu,
    float* __restrict__ mu_out)
{
    const int lane = threadIdx.x & 63;
    const int node = (blockIdx.x * 256 + threadIdx.x) >> 6;   // grid exact: always < NN
    const int j4 = lane << 2;
    const float4* xlv = (const float4*)xl;     // node row = 64 float4s

    const float4 xr4 = *(const float4*)&xr[(size_t)node * HC + j4];
    const float4 at4 = *(const float4*)&att[j4];
    const float4 w0  = *(const float4*)&We[j4];
    const float4 w1  = *(const float4*)&We[HC + j4];
    const float4 w2  = *(const float4*)&We[2 * HC + j4];

    float acc0 = 0.f, acc1 = 0.f, acc2 = 0.f, acc3 = 0.f, denom = 0.f;
    float eas0 = 0.f, eas1 = 0.f, eas2 = 0.f;
    const int beg = row_start[node];
    const int n   = row_start[node + 1] - beg;
    const float4* cp = csr + beg;

    float4 r0 = {0,0,0,0}, r1 = {0,0,0,0}, r2 = {0,0,0,0};
    float4 v0 = {0,0,0,0}, v1 = {0,0,0,0};
    if (n > 0) { r0 = cp[0]; v0 = xlv[(unsigned)(__float_as_int(r0.x) * 64 + lane)]; }
    if (n > 1) { r1 = cp[1]; v1 = xlv[(unsigned)(__float_as_int(r1.x) * 64 + lane)]; }
    if (n > 2) { r2 = cp[2]; }

    for (int i = 0; i < n; i++) {
        float4 crec = r0, cxv = v0;
        r0 = r1; r1 = r2; v0 = v1;
        if (i + 3 < n) r2 = cp[i + 3];
        if (i + 2 < n) v1 = xlv[(unsigned)(__float_as_int(r1.x) * 64 + lane)];

        float ea0 = crec.y, ea1 = crec.z, ea2 = crec.w;
        eas0 += ea0; eas1 += ea1; eas2 += ea2;
        float m0 = cxv.x + xr4.x + ea0 * w0.x + ea1 * w1.x + ea2 * w2.x;
        float m1 = cxv.y + xr4.y + ea0 * w0.y + ea1 * w1.y + ea2 * w2.y;
        float m2 = cxv.z + xr4.z + ea0 * w0.z + ea1 * w1.z + ea2 * w2.z;
        float m3 = cxv.w + xr4.w + ea0 * w0.w + ea1 * w1.w + ea2 * w2.w;
        m0 = fmaxf(m0, NSLOPE * m0);           // leaky-relu as single v_max
        m1 = fmaxf(m1, NSLOPE * m1);
        m2 = fmaxf(m2, NSLOPE * m2);
        m3 = fmaxf(m3, NSLOPE * m3);
        float p = m0 * at4.x + m1 * at4.y + m2 * at4.z + m3 * at4.w;
        p += __shfl_xor(p, 1);
        p += __shfl_xor(p, 2);
        p += __shfl_xor(p, 4);
        p += __shfl_xor(p, 8);
        // softmax shift-invariant; alpha O(1) so no max subtraction needed
        float ex = __expf(p);
        denom += ex;
        acc0 = fmaf(ex, cxv.x, acc0);
        acc1 = fmaf(ex, cxv.y, acc1);
        acc2 = fmaf(ex, cxv.z, acc2);
        acc3 = fmaf(ex, cxv.w, acc3);
    }

    {   // self loop: attr = mean of incoming edge attrs (0 if none)
        float rd = 1.0f / fmaxf((float)n, 1.0f);
        float ea0 = eas0 * rd, ea1 = eas1 * rd, ea2 = eas2 * rd;
        float4 sv = xlv[(unsigned)(node * 64 + lane)];
        float m0 = sv.x + xr4.x + ea0 * w0.x + ea1 * w1.x + ea2 * w2.x;
        float m1 = sv.y + xr4.y + ea0 * w0.y + ea1 * w1.y + ea2 * w2.y;
        float m2 = sv.z + xr4.z + ea0 * w0.z + ea1 * w1.z + ea2 * w2.z;
        float m3 = sv.w + xr4.w + ea0 * w0.w + ea1 * w1.w + ea2 * w2.w;
        m0 = fmaxf(m0, NSLOPE * m0);
        m1 = fmaxf(m1, NSLOPE * m1);
        m2 = fmaxf(m2, NSLOPE * m2);
        m3 = fmaxf(m3, NSLOPE * m3);
        float p = m0 * at4.x + m1 * at4.y + m2 * at4.z + m3 * at4.w;
        p += __shfl_xor(p, 1);
        p += __shfl_xor(p, 2);
        p += __shfl_xor(p, 4);
        p += __shfl_xor(p, 8);
        float ex = __expf(p);
        denom += ex;
        acc0 = fmaf(ex, sv.x, acc0);
        acc1 = fmaf(ex, sv.y, acc1);
        acc2 = fmaf(ex, sv.z, acc2);
        acc3 = fmaf(ex, sv.w, acc3);
    }

    const float inv = 1.0f / denom;
    float r0s = acc0 * inv, r1s = acc1 * inv, r2s = acc2 * inv, r3s = acc3 * inv;
    // head mean (butterfly: ALL lanes end up with the full head sum)
    r0s += __shfl_xor(r0s, 16); r0s += __shfl_xor(r0s, 32);
    r1s += __shfl_xor(r1s, 16); r1s += __shfl_xor(r1s, 32);
    r2s += __shfl_xor(r2s, 16); r2s += __shfl_xor(r2s, 32);
    r3s += __shfl_xor(r3s, 16); r3s += __shfl_xor(r3s, 32);

    if (FUSE) {
        // h[c] staged per wave in LDS, then out[n] = h @ Wmu + bmu (64x32)
        __shared__ float WmuS[64 * 32];
        __shared__ float bmuS[32];
        __shared__ float hsh[4][64];
        const int w = threadIdx.x >> 6;
        if (lane < 16) {
            float4 bv = *(const float4*)&bias[j4];
            float* hp = &hsh[w][j4];
            hp[0] = fmaxf(0.25f * r0s + bv.x, 0.f);
            hp[1] = fmaxf(0.25f * r1s + bv.y, 0.f);
            hp[2] = fmaxf(0.25f * r2s + bv.z, 0.f);
            hp[3] = fmaxf(0.25f * r3s + bv.w, 0.f);
        }
        for (int i = threadIdx.x; i < 2048; i += 256) WmuS[i] = Wmu[i];
        if (threadIdx.x < 32) bmuS[threadIdx.x] = bmu[threadIdx.x];
        __syncthreads();   // all 4 waves reach here exactly once (no early returns)
        const int o  = lane & 31;
        const int kh = (lane >> 5) << 5;
        float accm = 0.f;
#pragma unroll
        for (int k = 0; k < 32; k++)
            accm = fmaf(hsh[w][kh + k], WmuS[(kh + k) * 32 + o], accm);
        accm += __shfl_xor(accm, 32);
        if (lane < 32) mu_out[(size_t)node * 32 + o] = accm + bmuS[o];
    } else {
        if (lane < 16) {
            float4 bv = *(const float4*)&bias[j4];
            float4 oo;
            oo.x = fmaxf(0.25f * r0s + bv.x, 0.f);   // mean over H=4 heads, +bias, ReLU
            oo.y = fmaxf(0.25f * r1s + bv.y, 0.f);
            oo.z = fmaxf(0.25f * r2s + bv.z, 0.f);
            oo.w = fmaxf(0.25f * r3s + bv.w, 0.f);
            *(float4*)&out[(size_t)node * 64 + j4] = oo;
        }
    }
}

// ---------------- launch ----------------
extern "C" void kernel_launch(void* const* d_in, const int* in_sizes, int n_in,
                              void* d_out, int out_size, void* d_ws, size_t ws_size,
                              hipStream_t stream) {
    const float* x    = (const float*)d_in[0];
    const int*   ei   = (const int*)  d_in[1];
    const float* ea   = (const float*)d_in[2];
    const float* Wl0  = (const float*)d_in[3];
    const float* bl0  = (const float*)d_in[4];
    const float* Wr0  = (const float*)d_in[5];
    const float* br0  = (const float*)d_in[6];
    const float* We0  = (const float*)d_in[7];
    const float* att0 = (const float*)d_in[8];
    const float* bi0  = (const float*)d_in[9];
    const float* Wl1  = (const float*)d_in[10];
    const float* bl1  = (const float*)d_in[11];
    const float* Wr1  = (const float*)d_in[12];
    const float* br1  = (const float*)d_in[13];
    const float* We1  = (const float*)d_in[14];
    const float* att1 = (const float*)d_in[15];
    const float* bi1  = (const float*)d_in[16];
    const float* Wmu  = (const float*)d_in[17];
    const float* bmu  = (const float*)d_in[18];
    float* out = (float*)d_out;

    // workspace carve-up (~129.2 MB)
    float* xl32 = (float*)d_ws;                        // NN*256
    float* xr32 = xl32 + (size_t)NN * HC;              // NN*256
    float* h1   = xr32 + (size_t)NN * HC;              // NN*64
    int*   deg  = (int*)(h1 + (size_t)NN * 64);        // NN
    int*   rows = deg + NN;                            // NN+1
    int*   curs = rows + NN + 1;                       // NN
    int*   bsum = curs + NN;                           // SCAN_B
    int*   boff = bsum + SCAN_B;                       // SCAN_B
    uintptr_t p = (uintptr_t)(boff + SCAN_B);
    p = (p + 15) & ~(uintptr_t)15;
    unsigned short* WT0h = (unsigned short*)p;         // [512][256]
    unsigned short* WT0l = WT0h + 512 * 256;
    unsigned short* WT1h = WT0l + 512 * 256;           // [512][64]
    unsigned short* WT1l = WT1h + 512 * 64;
    p = (uintptr_t)(WT1l + 512 * 64);
    p = (p + 255) & ~(uintptr_t)255;
    float4* csr = (float4*)p;                          // EE records

    // single cooperative dispatch: zero + cvt + deg + scan + scatter
    BuildParams bp;
    bp.ei = ei;   bp.ea = ea;
    bp.deg = deg; bp.rows = rows; bp.curs = curs; bp.bsum = bsum; bp.boff = boff;
    bp.csr = csr;
    bp.Wl0 = Wl0; bp.Wr0 = Wr0; bp.Wl1 = Wl1; bp.Wr1 = Wr1;
    bp.WT0h = WT0h; bp.WT0l = WT0l; bp.WT1h = WT1h; bp.WT1l = WT1l;
    void* kargs[] = { &bp };
    hipLaunchCooperativeKernel((const void*)build_kernel,
                               dim3(NB_BUILD), dim3(256), kargs, 0, stream);

    dim3 gg(2, (NN + 63) / 64);
    const int gat_grid = (NN * 64) / 256;   // one wave per node (exact grid)

    // layer 0
    gemm_fused<<<gg, 256, 0, stream>>>(x, WT0h, WT0l, bl0, br0, xl32, xr32, NN, 256);
    gat_edge<0><<<gat_grid, 256, 0, stream>>>(xl32, xr32, csr, rows, att0, We0, bi0, h1,
                                              nullptr, nullptr, nullptr);

    // layer 1 (+ fused mu head -> final out)
    gemm_fused<<<gg, 256, 0, stream>>>(h1, WT1h, WT1l, bl1, br1, xl32, xr32, NN, 64);
    gat_edge<1><<<gat_grid, 256, 0, stream>>>(xl32, xr32, csr, rows, att1, We1, bi1, nullptr,
                                              Wmu, bmu, out);
}